// Round 1
// baseline (427.766 us; speedup 1.0000x reference)
//
#include <hip/hip_runtime.h>
#include <math.h>

// Problem constants (from reference)
#define T_DIM 1024
#define N_DIM 8192
#define M_TOT (T_DIM * N_DIM)

__device__ __constant__ float kGAMMA = 0.99f;
__device__ __constant__ float kGLAM  = 0.99f * 0.95f;   // gamma * gae_lambda

// ws layout:
//   acc[0] = sum(gae)          acc[1] = sum(gae^2)
//   acc[2] = action sum        acc[3] = value-term sum
//   acc[4] = entropy sum       acc[5] = mu   acc[6] = inv_(std+1e-5)
//   gae array at byte offset 256 (T*N floats = 32 MB)

__global__ void k_zero(double* __restrict__ acc) {
    if (threadIdx.x < 8) acc[threadIdx.x] = 0.0;
}

// K1: reverse GAE scan, one thread per env. Double-buffered batch prefetch.
__global__ __launch_bounds__(256) void k_scan(
    const float* __restrict__ rewards,
    const float* __restrict__ masks,
    const float* __restrict__ bad_masks,
    const float* __restrict__ value_preds,
    const float* __restrict__ last_value,
    float* __restrict__ gae_out,
    double* __restrict__ acc)
{
    const int n = blockIdx.x * blockDim.x + threadIdx.x;   // 0..N-1
    float vnext = last_value[n];
    float gae = 0.0f;
    float sg = 0.0f, sg2 = 0.0f;

    constexpr int B = 8;
    float rb[B], mb[B], bb[B], vb[B];

    int tb = T_DIM - B;
    #pragma unroll
    for (int i = 0; i < B; ++i) {
        const int t = tb + i;
        rb[i] = rewards[t * N_DIM + n];
        mb[i] = masks[(t + 1) * N_DIM + n];
        bb[i] = bad_masks[(t + 1) * N_DIM + n];
        vb[i] = value_preds[t * N_DIM + n];
    }

    while (true) {
        const int tn = tb - B;
        float rn[B], mn_[B], bn[B], vn[B];
        if (tn >= 0) {
            #pragma unroll
            for (int i = 0; i < B; ++i) {
                const int t = tn + i;
                rn[i]  = rewards[t * N_DIM + n];
                mn_[i] = masks[(t + 1) * N_DIM + n];
                bn[i]  = bad_masks[(t + 1) * N_DIM + n];
                vn[i]  = value_preds[t * N_DIM + n];
            }
        }
        // process current batch, descending t
        #pragma unroll
        for (int i = B - 1; i >= 0; --i) {
            const float m  = mb[i];
            const float delta = fmaf(kGAMMA * m, vnext, rb[i]) - vb[i];
            gae = fmaf(kGLAM * m, gae, delta) * bb[i];
            gae_out[(tb + i) * N_DIM + n] = gae;
            sg  += gae;
            sg2  = fmaf(gae, gae, sg2);
            vnext = vb[i];
        }
        if (tn < 0) break;
        #pragma unroll
        for (int i = 0; i < B; ++i) { rb[i]=rn[i]; mb[i]=mn_[i]; bb[i]=bn[i]; vb[i]=vn[i]; }
        tb = tn;
    }

    // block-reduce two sums into global double accumulators
    double d0 = (double)sg, d1 = (double)sg2;
    #pragma unroll
    for (int off = 32; off > 0; off >>= 1) {
        d0 += __shfl_down(d0, off, 64);
        d1 += __shfl_down(d1, off, 64);
    }
    __shared__ double sh[2][4];
    const int wid = threadIdx.x >> 6, lane = threadIdx.x & 63;
    if (lane == 0) { sh[0][wid] = d0; sh[1][wid] = d1; }
    __syncthreads();
    if (threadIdx.x == 0) {
        double t0 = 0.0, t1 = 0.0;
        #pragma unroll
        for (int w = 0; w < 4; ++w) { t0 += sh[0][w]; t1 += sh[1][w]; }
        atomicAdd(&acc[0], t0);
        atomicAdd(&acc[1], t1);
    }
}

// K2: finalize mean / inv(std+eps)
__global__ void k_stats(double* __restrict__ acc) {
    const double M = (double)M_TOT;
    const double sum = acc[0], sum2 = acc[1];
    const double mu = sum / M;
    double var = (sum2 - sum * sum / M) / (M - 1.0);
    if (var < 0.0) var = 0.0;
    acc[5] = mu;
    acc[6] = 1.0 / (sqrt(var) + 1e-5);
}

// K3: fused elementwise losses + reductions (full-BW parallel kernel)
__global__ __launch_bounds__(256) void k_main(
    const float4* __restrict__ gae,
    const float4* __restrict__ vp,        // value_preds rows 0..T-1 (flat [0, T*N))
    const float4* __restrict__ nv,        // new_value
    const float4* __restrict__ lp,        // log_prob
    const float4* __restrict__ plp,       // prev_log_prob
    const float4* __restrict__ ent,       // dist_entropy
    double* __restrict__ acc)
{
    const float mu   = (float)acc[5];
    const float invs = (float)acc[6];
    const int nvec = M_TOT / 4;

    float a_s = 0.0f, v_s = 0.0f, e_s = 0.0f;
    for (int i = blockIdx.x * blockDim.x + threadIdx.x; i < nvec;
         i += gridDim.x * blockDim.x) {
        const float4 g4 = gae[i];
        const float4 v4 = vp[i];
        const float4 n4 = nv[i];
        const float4 l4 = lp[i];
        const float4 p4 = plp[i];
        const float4 e4 = ent[i];
        const float gs[4] = {g4.x, g4.y, g4.z, g4.w};
        const float vs[4] = {v4.x, v4.y, v4.z, v4.w};
        const float ns[4] = {n4.x, n4.y, n4.z, n4.w};
        const float ls[4] = {l4.x, l4.y, l4.z, l4.w};
        const float ps[4] = {p4.x, p4.y, p4.z, p4.w};
        const float es[4] = {e4.x, e4.y, e4.z, e4.w};
        #pragma unroll
        for (int c = 0; c < 4; ++c) {
            const float x = (gs[c] - mu) * invs;            // normalized advantage
            const float r = __expf(ls[c] - ps[c]);          // ratio
            const float rc = fminf(fmaxf(r, 0.8f), 1.2f);   // clipped ratio
            a_s += fminf(r * x, rc * x);                    // min(surr1, surr2)
            const float v = vs[c];
            const float ret = gs[c] + v;                    // returns (value target)
            const float d = fminf(fmaxf(ns[c] - v, -0.2f), 0.2f);
            const float vpc = v + d;
            const float e1 = ns[c] - ret;
            const float e2 = vpc - ret;
            v_s += fmaxf(e1 * e1, e2 * e2);
            e_s += es[c];
        }
    }

    double d0 = (double)a_s, d1 = (double)v_s, d2 = (double)e_s;
    #pragma unroll
    for (int off = 32; off > 0; off >>= 1) {
        d0 += __shfl_down(d0, off, 64);
        d1 += __shfl_down(d1, off, 64);
        d2 += __shfl_down(d2, off, 64);
    }
    __shared__ double sh[3][4];
    const int wid = threadIdx.x >> 6, lane = threadIdx.x & 63;
    if (lane == 0) { sh[0][wid] = d0; sh[1][wid] = d1; sh[2][wid] = d2; }
    __syncthreads();
    if (threadIdx.x == 0) {
        double t0 = 0.0, t1 = 0.0, t2 = 0.0;
        #pragma unroll
        for (int w = 0; w < 4; ++w) { t0 += sh[0][w]; t1 += sh[1][w]; t2 += sh[2][w]; }
        atomicAdd(&acc[2], t0);
        atomicAdd(&acc[3], t1);
        atomicAdd(&acc[4], t2);
    }
}

// K4: final scalar loss
__global__ void k_final(const double* __restrict__ acc, float* __restrict__ out) {
    const double M = (double)M_TOT;
    // loss = 0.5*value_loss + action_loss - 0.01*ent_mean
    //      = 0.25*mean(value_term) - mean(min_surr) - 0.01*mean(ent)
    const double loss = 0.25 * acc[3] / M - acc[2] / M - 0.01 * acc[4] / M;
    out[0] = (float)loss;
}

extern "C" void kernel_launch(void* const* d_in, const int* in_sizes, int n_in,
                              void* d_out, int out_size, void* d_ws, size_t ws_size,
                              hipStream_t stream) {
    const float* rewards     = (const float*)d_in[0];  // (T, N)
    const float* masks       = (const float*)d_in[1];  // (T+1, N)
    const float* bad_masks   = (const float*)d_in[2];  // (T+1, N)
    const float* value_preds = (const float*)d_in[3];  // (T+1, N)
    const float* last_value  = (const float*)d_in[4];  // (N,)
    const float* log_prob    = (const float*)d_in[5];  // (T, N)
    const float* prev_lp     = (const float*)d_in[6];  // (T, N)
    const float* new_value   = (const float*)d_in[7];  // (T, N)
    const float* dist_ent    = (const float*)d_in[8];  // (T, N)

    double* acc = (double*)d_ws;
    float*  gae = (float*)((char*)d_ws + 256);

    k_zero<<<1, 64, 0, stream>>>(acc);
    k_scan<<<N_DIM / 256, 256, 0, stream>>>(rewards, masks, bad_masks,
                                            value_preds, last_value, gae, acc);
    k_stats<<<1, 1, 0, stream>>>(acc);
    k_main<<<2048, 256, 0, stream>>>((const float4*)gae,
                                     (const float4*)value_preds,
                                     (const float4*)new_value,
                                     (const float4*)log_prob,
                                     (const float4*)prev_lp,
                                     (const float4*)dist_ent,
                                     acc);
    k_final<<<1, 1, 0, stream>>>(acc, (float*)d_out);
}

// Round 2
// 367.939 us; speedup vs baseline: 1.1626x; 1.1626x over previous
//
#include <hip/hip_runtime.h>
#include <math.h>

// Problem constants (from reference)
#define T_DIM 1024
#define N_DIM 8192
#define M_TOT (T_DIM * N_DIM)
#define C_CHUNKS 64
#define L_CHUNK 16   // T_DIM / C_CHUNKS

__device__ __constant__ float kGAMMA = 0.99f;
__device__ __constant__ float kGLAM  = 0.99f * 0.95f;   // gamma * gae_lambda

// ws layout (total ~20.25 MB, well under the >=32MB proven in R1):
//   [0..64)        acc doubles: 0=sum g, 1=sum g^2, 2=action sum, 3=value sum,
//                  4=entropy sum, 5=mu, 6=inv(std+1e-5)
//   +256           A  [C][N] float (2 MB)  -- reused as g_in after k_ginc
//   +256+2MB       B  [C][N] float (2 MB)
//   +256+4MB       gae[T][N] bf16 (16 MB)

__device__ __forceinline__ unsigned short f2bf(float f) {
    unsigned int u = __float_as_uint(f);
    u += 0x7fffu + ((u >> 16) & 1u);       // round-to-nearest-even
    return (unsigned short)(u >> 16);
}
__device__ __forceinline__ float bf2f(unsigned short h) {
    return __uint_as_float(((unsigned int)h) << 16);
}

__global__ void k_zero(double* __restrict__ acc) {
    if (threadIdx.x < 8) acc[threadIdx.x] = 0.0;
}

// ---------------------------------------------------------------------------
// K1: per (chunk, env) compose the chunk's 16 affine steps into (A, B).
// g_out = A * g_in + B  where g_in enters from the later (t-higher) chunk.
__global__ __launch_bounds__(256) void k_chunkAB(
    const float* __restrict__ rewards,
    const float* __restrict__ masks,
    const float* __restrict__ bad_masks,
    const float* __restrict__ value_preds,
    const float* __restrict__ last_value,
    float* __restrict__ A_out,
    float* __restrict__ B_out)
{
    const int g  = blockIdx.x * blockDim.x + threadIdx.x;  // 0 .. C*N-1
    const int n  = g & (N_DIM - 1);
    const int c  = g >> 13;                                // log2(N_DIM)
    const int t0 = c * L_CHUNK;

    float rr[L_CHUNK], mm[L_CHUNK], bb[L_CHUNK], vv[L_CHUNK];
    #pragma unroll
    for (int i = 0; i < L_CHUNK; ++i) {
        const int t = t0 + i;
        rr[i] = rewards[t * N_DIM + n];
        mm[i] = masks[(t + 1) * N_DIM + n];
        bb[i] = bad_masks[(t + 1) * N_DIM + n];
        vv[i] = value_preds[t * N_DIM + n];
    }
    const float vlast = (c == C_CHUNKS - 1) ? last_value[n]
                                            : value_preds[(t0 + L_CHUNK) * N_DIM + n];

    float Aa = 1.0f, Bb = 0.0f;
    #pragma unroll
    for (int i = L_CHUNK - 1; i >= 0; --i) {
        const float vn    = (i == L_CHUNK - 1) ? vlast : vv[i + 1];
        const float delta = fmaf(kGAMMA * mm[i], vn, rr[i]) - vv[i];
        const float a     = kGLAM * mm[i] * bb[i];
        const float b     = delta * bb[i];
        Aa = a * Aa;
        Bb = fmaf(a, Bb, b);
    }
    A_out[c * N_DIM + n] = Aa;
    B_out[c * N_DIM + n] = Bb;
}

// ---------------------------------------------------------------------------
// K2: per env, serial scan over the 64 chunk maps; writes each chunk's
// incoming gae. g_in output ALIASES A (safe: batch-load A,B then store).
__global__ __launch_bounds__(256) void k_ginc(
    const float* __restrict__ A_in,
    const float* __restrict__ B_in,
    float* __restrict__ g_in)   // may alias A_in
{
    const int n = blockIdx.x * blockDim.x + threadIdx.x;   // 0..N-1
    float g = 0.0f;
    constexpr int PB = 16;
    for (int cb = C_CHUNKS - PB; cb >= 0; cb -= PB) {
        float Ar[PB], Br[PB];
        #pragma unroll
        for (int i = 0; i < PB; ++i) {
            Ar[i] = A_in[(cb + i) * N_DIM + n];
            Br[i] = B_in[(cb + i) * N_DIM + n];
        }
        #pragma unroll
        for (int i = PB - 1; i >= 0; --i) {
            g_in[(cb + i) * N_DIM + n] = g;
            g = fmaf(Ar[i], g, Br[i]);
        }
    }
}

// ---------------------------------------------------------------------------
// K3: per (chunk, env): recompute gae elementwise from g_in; write bf16 gae;
// fuse value-loss, entropy, and sum/sum2 reductions.
__global__ __launch_bounds__(256) void k_gae_fused(
    const float* __restrict__ rewards,
    const float* __restrict__ masks,
    const float* __restrict__ bad_masks,
    const float* __restrict__ value_preds,
    const float* __restrict__ last_value,
    const float* __restrict__ new_value,
    const float* __restrict__ dist_ent,
    const float* __restrict__ g_in,
    unsigned short* __restrict__ gae16,
    double* __restrict__ acc)
{
    const int g  = blockIdx.x * blockDim.x + threadIdx.x;
    const int n  = g & (N_DIM - 1);
    const int c  = g >> 13;
    const int t0 = c * L_CHUNK;

    float rr[L_CHUNK], mm[L_CHUNK], bb[L_CHUNK], vv[L_CHUNK], nn[L_CHUNK], ee[L_CHUNK];
    #pragma unroll
    for (int i = 0; i < L_CHUNK; ++i) {
        const int t = t0 + i;
        rr[i] = rewards[t * N_DIM + n];
        mm[i] = masks[(t + 1) * N_DIM + n];
        bb[i] = bad_masks[(t + 1) * N_DIM + n];
        vv[i] = value_preds[t * N_DIM + n];
        nn[i] = new_value[t * N_DIM + n];
        ee[i] = dist_ent[t * N_DIM + n];
    }
    const float vlast = (c == C_CHUNKS - 1) ? last_value[n]
                                            : value_preds[(t0 + L_CHUNK) * N_DIM + n];

    float gae = g_in[c * N_DIM + n];
    float sg = 0.0f, sg2 = 0.0f, v_s = 0.0f, e_s = 0.0f;
    #pragma unroll
    for (int i = L_CHUNK - 1; i >= 0; --i) {
        const float vn    = (i == L_CHUNK - 1) ? vlast : vv[i + 1];
        const float delta = fmaf(kGAMMA * mm[i], vn, rr[i]) - vv[i];
        gae = fmaf(kGLAM * mm[i], gae, delta) * bb[i];
        gae16[(t0 + i) * N_DIM + n] = f2bf(gae);
        sg  += gae;
        sg2  = fmaf(gae, gae, sg2);
        const float v   = vv[i];
        const float ret = gae + v;                          // value target
        const float d   = fminf(fmaxf(nn[i] - v, -0.2f), 0.2f);
        const float e1  = nn[i] - ret;
        const float e2  = (v + d) - ret;
        v_s += fmaxf(e1 * e1, e2 * e2);
        e_s += ee[i];
    }

    double d0 = (double)sg, d1 = (double)sg2, d2 = (double)v_s, d3 = (double)e_s;
    #pragma unroll
    for (int off = 32; off > 0; off >>= 1) {
        d0 += __shfl_down(d0, off, 64);
        d1 += __shfl_down(d1, off, 64);
        d2 += __shfl_down(d2, off, 64);
        d3 += __shfl_down(d3, off, 64);
    }
    __shared__ double sh[4][4];
    const int wid = threadIdx.x >> 6, lane = threadIdx.x & 63;
    if (lane == 0) { sh[0][wid] = d0; sh[1][wid] = d1; sh[2][wid] = d2; sh[3][wid] = d3; }
    __syncthreads();
    if (threadIdx.x == 0) {
        double t0s = 0, t1s = 0, t2s = 0, t3s = 0;
        #pragma unroll
        for (int w = 0; w < 4; ++w) { t0s += sh[0][w]; t1s += sh[1][w]; t2s += sh[2][w]; t3s += sh[3][w]; }
        atomicAdd(&acc[0], t0s);
        atomicAdd(&acc[1], t1s);
        atomicAdd(&acc[3], t2s);
        atomicAdd(&acc[4], t3s);
    }
}

// ---------------------------------------------------------------------------
__global__ void k_stats(double* __restrict__ acc) {
    const double M = (double)M_TOT;
    const double sum = acc[0], sum2 = acc[1];
    const double mu = sum / M;
    double var = (sum2 - sum * sum / M) / (M - 1.0);
    if (var < 0.0) var = 0.0;
    acc[5] = mu;
    acc[6] = 1.0 / (sqrt(var) + 1e-5);
}

// ---------------------------------------------------------------------------
// K5: action loss over gae(bf16) + log_prob + prev_log_prob.
__global__ __launch_bounds__(256) void k_action(
    const ushort4* __restrict__ gae16,
    const float4* __restrict__ lp,
    const float4* __restrict__ plp,
    double* __restrict__ acc)
{
    const float mu   = (float)acc[5];
    const float invs = (float)acc[6];
    const int nvec = M_TOT / 4;

    float a_s = 0.0f;
    for (int i = blockIdx.x * blockDim.x + threadIdx.x; i < nvec;
         i += gridDim.x * blockDim.x) {
        const ushort4 g4 = gae16[i];
        const float4  l4 = lp[i];
        const float4  p4 = plp[i];
        const float gs[4] = {bf2f(g4.x), bf2f(g4.y), bf2f(g4.z), bf2f(g4.w)};
        const float ls[4] = {l4.x, l4.y, l4.z, l4.w};
        const float ps[4] = {p4.x, p4.y, p4.z, p4.w};
        #pragma unroll
        for (int cidx = 0; cidx < 4; ++cidx) {
            const float x  = (gs[cidx] - mu) * invs;
            const float r  = __expf(ls[cidx] - ps[cidx]);
            const float rc = fminf(fmaxf(r, 0.8f), 1.2f);
            a_s += fminf(r * x, rc * x);
        }
    }

    double d0 = (double)a_s;
    #pragma unroll
    for (int off = 32; off > 0; off >>= 1) d0 += __shfl_down(d0, off, 64);
    __shared__ double sh[4];
    const int wid = threadIdx.x >> 6, lane = threadIdx.x & 63;
    if (lane == 0) sh[wid] = d0;
    __syncthreads();
    if (threadIdx.x == 0) {
        double t0s = sh[0] + sh[1] + sh[2] + sh[3];
        atomicAdd(&acc[2], t0s);
    }
}

// ---------------------------------------------------------------------------
__global__ void k_final(const double* __restrict__ acc, float* __restrict__ out) {
    const double M = (double)M_TOT;
    const double loss = 0.25 * acc[3] / M - acc[2] / M - 0.01 * acc[4] / M;
    out[0] = (float)loss;
}

extern "C" void kernel_launch(void* const* d_in, const int* in_sizes, int n_in,
                              void* d_out, int out_size, void* d_ws, size_t ws_size,
                              hipStream_t stream) {
    const float* rewards     = (const float*)d_in[0];
    const float* masks       = (const float*)d_in[1];
    const float* bad_masks   = (const float*)d_in[2];
    const float* value_preds = (const float*)d_in[3];
    const float* last_value  = (const float*)d_in[4];
    const float* log_prob    = (const float*)d_in[5];
    const float* prev_lp     = (const float*)d_in[6];
    const float* new_value   = (const float*)d_in[7];
    const float* dist_ent    = (const float*)d_in[8];

    char* ws = (char*)d_ws;
    double* acc = (double*)ws;
    float*  A   = (float*)(ws + 256);
    float*  B   = (float*)(ws + 256 + (size_t)C_CHUNKS * N_DIM * 4);
    unsigned short* gae16 = (unsigned short*)(ws + 256 + (size_t)2 * C_CHUNKS * N_DIM * 4);

    const int cn_blocks = (C_CHUNKS * N_DIM) / 256;   // 2048

    k_zero<<<1, 64, 0, stream>>>(acc);
    k_chunkAB<<<cn_blocks, 256, 0, stream>>>(rewards, masks, bad_masks,
                                             value_preds, last_value, A, B);
    k_ginc<<<N_DIM / 256, 256, 0, stream>>>(A, B, A /* g_in aliases A */);
    k_gae_fused<<<cn_blocks, 256, 0, stream>>>(rewards, masks, bad_masks,
                                               value_preds, last_value, new_value,
                                               dist_ent, A /* g_in */, gae16, acc);
    k_stats<<<1, 1, 0, stream>>>(acc);
    k_action<<<2048, 256, 0, stream>>>((const ushort4*)gae16,
                                       (const float4*)log_prob,
                                       (const float4*)prev_lp, acc);
    k_final<<<1, 1, 0, stream>>>(acc, (float*)d_out);
}

// Round 3
// 337.415 us; speedup vs baseline: 1.2678x; 1.0905x over previous
//
#include <hip/hip_runtime.h>
#include <math.h>

// Problem constants
#define T_DIM 1024
#define N_DIM 8192
#define M_TOT (T_DIM * N_DIM)      // 8,388,608
#define NVEC  (M_TOT / 4)          // 2,097,152 float4 elements
#define NV4   (N_DIM / 4)          // 2048 float4 per row
#define L_CHUNK 8
#define C_CHUNKS 128               // T_DIM / L_CHUNK

#define kGAMMA 0.99f
#define kGLAM  (0.99f * 0.95f)

// ws layout (25.2 MB total; <= 32.25 MB proven available in R1):
//   [0, 512)       acc doubles: 0=sum g, 1=sum g^2, 2=action sum, 3=value sum,
//                  4=entropy sum, 5=mu, 6=inv(std+1e-5)
//   +512           b16 [T][N] ushort (16 MB) -- k_gae overwrites with gae16
//   +512+16MB      A [C][N] float (4 MB)     -- k_ginc overwrites with g_in
//   +512+20MB      B [C][N] float (4 MB)

__device__ __forceinline__ unsigned short f2bf(float f) {
    unsigned int u = __float_as_uint(f);
    u += 0x7fffu + ((u >> 16) & 1u);        // round-to-nearest-even
    return (unsigned short)(u >> 16);
}
__device__ __forceinline__ float bf2f(unsigned short h) {
    return __uint_as_float(((unsigned int)h) << 16);
}

__global__ void k_zero(double* __restrict__ acc) {
    if (threadIdx.x < 8) acc[threadIdx.x] = 0.0;
}

// ---------------------------------------------------------------------------
// P1: pure streaming elementwise: b_t = (r + g*m*v_next - v) * bb, stored bf16
// with the a-bit (m*bb != 0) packed in the LSB. a decode is then EXACT.
__global__ __launch_bounds__(256) void k_prep(
    const float4* __restrict__ r4,
    const float4* __restrict__ m4,     // (T+1) rows
    const float4* __restrict__ bm4,    // (T+1) rows
    const float4* __restrict__ vp4,    // (T+1) rows
    const float4* __restrict__ lv4,    // (N,)
    ushort4* __restrict__ b16)
{
    for (int i = blockIdx.x * 256 + threadIdx.x; i < NVEC; i += gridDim.x * 256) {
        const int t = i >> 11;                       // i / NV4
        const float4 r  = r4[i];
        const float4 v  = vp4[i];
        const float4 m  = m4[i + NV4];               // row t+1
        const float4 bb = bm4[i + NV4];              // row t+1
        float4 vn;
        if (t == T_DIM - 1) vn = lv4[i - (T_DIM - 1) * NV4];
        else                vn = vp4[i + NV4];

        ushort4 o;
        {
            float b = (fmaf(kGAMMA * m.x, vn.x, r.x) - v.x) * bb.x;
            unsigned short bit = (m.x * bb.x > 0.5f) ? 1u : 0u;
            o.x = (unsigned short)((f2bf(b) & 0xFFFEu) | bit);
        }
        {
            float b = (fmaf(kGAMMA * m.y, vn.y, r.y) - v.y) * bb.y;
            unsigned short bit = (m.y * bb.y > 0.5f) ? 1u : 0u;
            o.y = (unsigned short)((f2bf(b) & 0xFFFEu) | bit);
        }
        {
            float b = (fmaf(kGAMMA * m.z, vn.z, r.z) - v.z) * bb.z;
            unsigned short bit = (m.z * bb.z > 0.5f) ? 1u : 0u;
            o.z = (unsigned short)((f2bf(b) & 0xFFFEu) | bit);
        }
        {
            float b = (fmaf(kGAMMA * m.w, vn.w, r.w) - v.w) * bb.w;
            unsigned short bit = (m.w * bb.w > 0.5f) ? 1u : 0u;
            o.w = (unsigned short)((f2bf(b) & 0xFFFEu) | bit);
        }
        b16[i] = o;
    }
}

// ---------------------------------------------------------------------------
// P2: compose per-chunk affine maps (A,B) over L=8 steps from b16.
__device__ __forceinline__ void stepAB(float& A, float& B, unsigned short h) {
    const float bf = bf2f(h);
    const float a  = (h & 1u) ? kGLAM : 0.0f;
    A = a * A;
    B = fmaf(a, B, bf);
}

__global__ __launch_bounds__(256) void k_chunk(
    const ushort4* __restrict__ b16,
    float4* __restrict__ A_out,
    float4* __restrict__ B_out)
{
    const int g = blockIdx.x * 256 + threadIdx.x;   // 0 .. C*NV4-1
    const int j = g & (NV4 - 1);
    const int c = g >> 11;
    const int t0 = c * L_CHUNK;

    ushort4 bq[L_CHUNK];
    #pragma unroll
    for (int i = 0; i < L_CHUNK; ++i) bq[i] = b16[(t0 + i) * NV4 + j];

    float4 Aa = make_float4(1.f, 1.f, 1.f, 1.f);
    float4 Bb = make_float4(0.f, 0.f, 0.f, 0.f);
    #pragma unroll
    for (int i = L_CHUNK - 1; i >= 0; --i) {
        stepAB(Aa.x, Bb.x, bq[i].x);
        stepAB(Aa.y, Bb.y, bq[i].y);
        stepAB(Aa.z, Bb.z, bq[i].z);
        stepAB(Aa.w, Bb.w, bq[i].w);
    }
    A_out[c * NV4 + j] = Aa;
    B_out[c * NV4 + j] = Bb;
}

// ---------------------------------------------------------------------------
// P3: per-env serial scan over the 128 chunk maps; writes each chunk's
// incoming gae. g_in ALIASES A (load batch, then store over it).
__global__ __launch_bounds__(256) void k_ginc(
    const float* __restrict__ A_in,
    const float* __restrict__ B_in,
    float* __restrict__ g_in)          // aliases A_in
{
    const int n = blockIdx.x * 256 + threadIdx.x;   // 0..N-1
    float g = 0.0f;
    constexpr int PB = 16;
    for (int cb = C_CHUNKS - PB; cb >= 0; cb -= PB) {
        float Ar[PB], Br[PB];
        #pragma unroll
        for (int i = 0; i < PB; ++i) {
            Ar[i] = A_in[(cb + i) * N_DIM + n];
            Br[i] = B_in[(cb + i) * N_DIM + n];
        }
        #pragma unroll
        for (int i = PB - 1; i >= 0; --i) {
            g_in[(cb + i) * N_DIM + n] = g;
            g = fmaf(Ar[i], g, Br[i]);
        }
    }
}

// ---------------------------------------------------------------------------
// P4: recompute gae per element (2-op chain on b16), write gae16 in place,
// fuse value loss (reads vp, nv) and sum/sum2 of gae.
__device__ __forceinline__ void gae_comp(float& gae, unsigned short h,
                                         float v, float nvv,
                                         float& sg, float& sg2, float& v_s) {
    const float bf = bf2f(h);
    const float a  = (h & 1u) ? kGLAM : 0.0f;
    gae = fmaf(a, gae, bf);
    sg += gae;
    sg2 = fmaf(gae, gae, sg2);
    const float q  = nvv - v;
    const float e1 = q - gae;
    const float e2 = fminf(fmaxf(q, -0.2f), 0.2f) - gae;
    v_s += fmaxf(e1 * e1, e2 * e2);
}

__global__ __launch_bounds__(256) void k_gae(
    ushort4* __restrict__ bg16,        // in: b16, out: gae16
    const float4* __restrict__ g_in4,
    const float4* __restrict__ vp4,
    const float4* __restrict__ nv4,
    double* __restrict__ acc)
{
    const int g = blockIdx.x * 256 + threadIdx.x;   // 0 .. C*NV4-1
    const int j = g & (NV4 - 1);
    const int c = g >> 11;
    const int t0 = c * L_CHUNK;

    ushort4 bq[L_CHUNK];
    float4 vv[L_CHUNK], nn[L_CHUNK];
    #pragma unroll
    for (int i = 0; i < L_CHUNK; ++i) {
        const int idx = (t0 + i) * NV4 + j;
        bq[i] = bg16[idx];
        vv[i] = vp4[idx];
        nn[i] = nv4[idx];
    }

    float4 gae = g_in4[c * NV4 + j];
    float sg = 0.f, sg2 = 0.f, v_s = 0.f;
    #pragma unroll
    for (int i = L_CHUNK - 1; i >= 0; --i) {
        gae_comp(gae.x, bq[i].x, vv[i].x, nn[i].x, sg, sg2, v_s);
        gae_comp(gae.y, bq[i].y, vv[i].y, nn[i].y, sg, sg2, v_s);
        gae_comp(gae.z, bq[i].z, vv[i].z, nn[i].z, sg, sg2, v_s);
        gae_comp(gae.w, bq[i].w, vv[i].w, nn[i].w, sg, sg2, v_s);
        ushort4 o;
        o.x = f2bf(gae.x); o.y = f2bf(gae.y); o.z = f2bf(gae.z); o.w = f2bf(gae.w);
        bg16[(t0 + i) * NV4 + j] = o;
    }

    double d0 = (double)sg, d1 = (double)sg2, d2 = (double)v_s;
    #pragma unroll
    for (int off = 32; off > 0; off >>= 1) {
        d0 += __shfl_down(d0, off, 64);
        d1 += __shfl_down(d1, off, 64);
        d2 += __shfl_down(d2, off, 64);
    }
    __shared__ double sh[3][4];
    const int wid = threadIdx.x >> 6, lane = threadIdx.x & 63;
    if (lane == 0) { sh[0][wid] = d0; sh[1][wid] = d1; sh[2][wid] = d2; }
    __syncthreads();
    if (threadIdx.x == 0) {
        double t0s = 0, t1s = 0, t2s = 0;
        #pragma unroll
        for (int w = 0; w < 4; ++w) { t0s += sh[0][w]; t1s += sh[1][w]; t2s += sh[2][w]; }
        atomicAdd(&acc[0], t0s);
        atomicAdd(&acc[1], t1s);
        atomicAdd(&acc[3], t2s);
    }
}

// ---------------------------------------------------------------------------
__global__ void k_stats(double* __restrict__ acc) {
    const double M = (double)M_TOT;
    const double sum = acc[0], sum2 = acc[1];
    const double mu = sum / M;
    double var = (sum2 - sum * sum / M) / (M - 1.0);
    if (var < 0.0) var = 0.0;
    acc[5] = mu;
    acc[6] = 1.0 / (sqrt(var) + 1e-5);
}

// ---------------------------------------------------------------------------
// P5: action loss + entropy (streaming).
__global__ __launch_bounds__(256) void k_loss(
    const ushort4* __restrict__ gae16,
    const float4* __restrict__ lp4,
    const float4* __restrict__ plp4,
    const float4* __restrict__ ent4,
    double* __restrict__ acc)
{
    const float mu   = (float)acc[5];
    const float invs = (float)acc[6];

    float a_s = 0.f, e_s = 0.f;
    for (int i = blockIdx.x * 256 + threadIdx.x; i < NVEC; i += gridDim.x * 256) {
        const ushort4 g4 = gae16[i];
        const float4  l4 = lp4[i];
        const float4  p4 = plp4[i];
        const float4  e4 = ent4[i];
        const float gs[4] = {bf2f(g4.x), bf2f(g4.y), bf2f(g4.z), bf2f(g4.w)};
        const float ls[4] = {l4.x, l4.y, l4.z, l4.w};
        const float ps[4] = {p4.x, p4.y, p4.z, p4.w};
        #pragma unroll
        for (int c = 0; c < 4; ++c) {
            const float x  = (gs[c] - mu) * invs;
            const float r  = __expf(ls[c] - ps[c]);
            const float rc = fminf(fmaxf(r, 0.8f), 1.2f);
            a_s += fminf(r * x, rc * x);
        }
        e_s += e4.x + e4.y + e4.z + e4.w;
    }

    double d0 = (double)a_s, d1 = (double)e_s;
    #pragma unroll
    for (int off = 32; off > 0; off >>= 1) {
        d0 += __shfl_down(d0, off, 64);
        d1 += __shfl_down(d1, off, 64);
    }
    __shared__ double sh[2][4];
    const int wid = threadIdx.x >> 6, lane = threadIdx.x & 63;
    if (lane == 0) { sh[0][wid] = d0; sh[1][wid] = d1; }
    __syncthreads();
    if (threadIdx.x == 0) {
        double t0s = 0, t1s = 0;
        #pragma unroll
        for (int w = 0; w < 4; ++w) { t0s += sh[0][w]; t1s += sh[1][w]; }
        atomicAdd(&acc[2], t0s);
        atomicAdd(&acc[4], t1s);
    }
}

// ---------------------------------------------------------------------------
__global__ void k_final(const double* __restrict__ acc, float* __restrict__ out) {
    const double M = (double)M_TOT;
    const double loss = 0.25 * acc[3] / M - acc[2] / M - 0.01 * acc[4] / M;
    out[0] = (float)loss;
}

extern "C" void kernel_launch(void* const* d_in, const int* in_sizes, int n_in,
                              void* d_out, int out_size, void* d_ws, size_t ws_size,
                              hipStream_t stream) {
    const float* rewards     = (const float*)d_in[0];   // (T, N)
    const float* masks       = (const float*)d_in[1];   // (T+1, N)
    const float* bad_masks   = (const float*)d_in[2];   // (T+1, N)
    const float* value_preds = (const float*)d_in[3];   // (T+1, N)
    const float* last_value  = (const float*)d_in[4];   // (N,)
    const float* log_prob    = (const float*)d_in[5];   // (T, N)
    const float* prev_lp     = (const float*)d_in[6];   // (T, N)
    const float* new_value   = (const float*)d_in[7];   // (T, N)
    const float* dist_ent    = (const float*)d_in[8];   // (T, N)

    char* ws = (char*)d_ws;
    double* acc = (double*)ws;
    unsigned short* b16 = (unsigned short*)(ws + 512);
    float* A = (float*)(ws + 512 + (size_t)M_TOT * 2);
    float* B = (float*)(ws + 512 + (size_t)M_TOT * 2 + (size_t)C_CHUNKS * N_DIM * 4);

    k_zero<<<1, 64, 0, stream>>>(acc);
    k_prep<<<2048, 256, 0, stream>>>((const float4*)rewards,
                                     (const float4*)masks,
                                     (const float4*)bad_masks,
                                     (const float4*)value_preds,
                                     (const float4*)last_value,
                                     (ushort4*)b16);
    k_chunk<<<(C_CHUNKS * NV4) / 256, 256, 0, stream>>>((const ushort4*)b16,
                                                        (float4*)A, (float4*)B);
    k_ginc<<<N_DIM / 256, 256, 0, stream>>>(A, B, A /* g_in aliases A */);
    k_gae<<<(C_CHUNKS * NV4) / 256, 256, 0, stream>>>((ushort4*)b16,
                                                      (const float4*)A /* g_in */,
                                                      (const float4*)value_preds,
                                                      (const float4*)new_value,
                                                      acc);
    k_stats<<<1, 1, 0, stream>>>(acc);
    k_loss<<<2048, 256, 0, stream>>>((const ushort4*)b16 /* now gae16 */,
                                     (const float4*)log_prob,
                                     (const float4*)prev_lp,
                                     (const float4*)dist_ent,
                                     acc);
    k_final<<<1, 1, 0, stream>>>(acc, (float*)d_out);
}